// Round 1
// baseline (74.312 us; speedup 1.0000x reference)
//
#include <hip/hip_runtime.h>

#define NS   256
#define DIN  512
#define DHID 1024

// ---------------- Kernel A: feature pass ----------------
// Z = [x1;x2] @ W1 + b1  (rows 0..255 = x1, 256..511 = x2)
// H = relu(Z); G = (Z>0) * w2
// grid (16,16): blockIdx.x = 64-col chunk, blockIdx.y = 32-row chunk. block 512.
__global__ __launch_bounds__(512) void feat_kernel(
    const float* __restrict__ x1, const float* __restrict__ x2,
    const float* __restrict__ W1, const float* __restrict__ b1,
    const float* __restrict__ w2,
    float* __restrict__ H, float* __restrict__ G)
{
    __shared__ float xs[32][DIN];                 // 64 KiB
    const int tid  = threadIdx.x;
    const int col  = blockIdx.x * 64 + (tid & 63);
    const int rg   = tid >> 6;                    // 0..7 (wave-uniform)
    const int row0 = blockIdx.y * 32;

    // stage 32 rows x 512 floats = 4096 float4, 512 threads -> 8 each (coalesced)
    const float* src = (row0 < NS) ? (x1 + row0 * DIN) : (x2 + (row0 - NS) * DIN);
    #pragma unroll
    for (int i = 0; i < 8; ++i) {
        int f  = i * 512 + tid;       // float4 index 0..4095
        int r  = f >> 7;              // /128
        int c4 = (f & 127) << 2;
        *reinterpret_cast<float4*>(&xs[r][c4]) =
            *reinterpret_cast<const float4*>(src + r * DIN + c4);
    }
    __syncthreads();

    float a0 = 0.f, a1 = 0.f, a2 = 0.f, a3 = 0.f;
    const int r0 = rg * 4;
    #pragma unroll 8
    for (int a = 0; a < DIN; ++a) {
        float w = W1[a * DHID + col];             // coalesced; L1-reused across waves
        a0 = fmaf(xs[r0 + 0][a], w, a0);          // LDS broadcast (wave-uniform addr)
        a1 = fmaf(xs[r0 + 1][a], w, a1);
        a2 = fmaf(xs[r0 + 2][a], w, a2);
        a3 = fmaf(xs[r0 + 3][a], w, a3);
    }

    const float bb = b1[col];
    const float ww = w2[col];
    float acc[4] = {a0, a1, a2, a3};
    #pragma unroll
    for (int r = 0; r < 4; ++r) {
        float z = acc[r] + bb;
        int row = row0 + r0 + r;
        H[row * DHID + col] = z > 0.f ? z  : 0.f;
        G[row * DHID + col] = z > 0.f ? ww : 0.f;
    }
}

// ---------------- Kernel B: fused gram + combine ----------------
// K[i,j] = (x1_i . x2_j + 1) * (g1_i . g2_j) + h1_i . h2_j + 1
// grid (16,16): 16x16 output tile per block of 256 threads.
__global__ __launch_bounds__(256) void ntk_kernel(
    const float* __restrict__ x1, const float* __restrict__ x2,
    const float* __restrict__ H, const float* __restrict__ G,
    float* __restrict__ out)
{
    const int tid = threadIdx.x;
    const int tj  = tid & 15;
    const int ti  = tid >> 4;
    const int bi  = blockIdx.y * 16;
    const int bj  = blockIdx.x * 16;

    // pad 68: bank = (row*68 + t) % 32 = (row*4 + t) % 32 -> worst 2-way (free, m136)
    __shared__ float sA[16][68], sB[16][68], sC[16][68], sD[16][68];

    float acc_c = 0.f, acc_g = 0.f, acc_h = 0.f;

    const int lr = tid >> 4;            // 0..15 staging row
    const int c4 = (tid & 15) << 2;     // 0..60 staging col (float4)

    // ---- x1 . x2 over DIN=512, 8 chunks of 64 ----
    for (int ch = 0; ch < 8; ++ch) {
        int off = ch * 64 + c4;
        *reinterpret_cast<float4*>(&sA[lr][c4]) =
            *reinterpret_cast<const float4*>(x1 + (bi + lr) * DIN + off);
        *reinterpret_cast<float4*>(&sB[lr][c4]) =
            *reinterpret_cast<const float4*>(x2 + (bj + lr) * DIN + off);
        __syncthreads();
        #pragma unroll
        for (int t = 0; t < 64; ++t)
            acc_c = fmaf(sA[ti][t], sB[tj][t], acc_c);
        __syncthreads();
    }

    // ---- g1.g2 and h1.h2 over DHID=1024, 16 chunks of 64 ----
    const float* G1 = G;
    const float* G2 = G + NS * DHID;
    const float* H1 = H;
    const float* H2 = H + NS * DHID;
    for (int ch = 0; ch < 16; ++ch) {
        int off = ch * 64 + c4;
        *reinterpret_cast<float4*>(&sA[lr][c4]) =
            *reinterpret_cast<const float4*>(G1 + (bi + lr) * DHID + off);
        *reinterpret_cast<float4*>(&sB[lr][c4]) =
            *reinterpret_cast<const float4*>(G2 + (bj + lr) * DHID + off);
        *reinterpret_cast<float4*>(&sC[lr][c4]) =
            *reinterpret_cast<const float4*>(H1 + (bi + lr) * DHID + off);
        *reinterpret_cast<float4*>(&sD[lr][c4]) =
            *reinterpret_cast<const float4*>(H2 + (bj + lr) * DHID + off);
        __syncthreads();
        #pragma unroll
        for (int t = 0; t < 64; ++t) {
            acc_g = fmaf(sA[ti][t], sB[tj][t], acc_g);
            acc_h = fmaf(sC[ti][t], sD[tj][t], acc_h);
        }
        __syncthreads();
    }

    out[(bi + ti) * NS + (bj + tj)] = (acc_c + 1.f) * acc_g + acc_h + 1.f;
}

extern "C" void kernel_launch(void* const* d_in, const int* in_sizes, int n_in,
                              void* d_out, int out_size, void* d_ws, size_t ws_size,
                              hipStream_t stream) {
    const float* x1 = (const float*)d_in[0];   // [256,512]
    const float* x2 = (const float*)d_in[1];   // [256,512]
    const float* W1 = (const float*)d_in[2];   // [512,1024]
    const float* b1 = (const float*)d_in[3];   // [1024]
    const float* W2 = (const float*)d_in[4];   // [1024,1] -> w2 vector
    // d_in[5] = b2: gradient w.r.t. b2 is 1 regardless of its value -> "+1" term.

    float* H = (float*)d_ws;                   // [512,1024]
    float* G = H + 512 * 1024;                 // [512,1024]
    float* out = (float*)d_out;                // [256,256]

    feat_kernel<<<dim3(16, 16), 512, 0, stream>>>(x1, x2, W1, b1, W2, H, G);
    ntk_kernel<<<dim3(16, 16), 256, 0, stream>>>(x1, x2, H, G, out);
}

// Round 2
// 26.980 us; speedup vs baseline: 2.7543x; 2.7543x over previous
//
#include <hip/hip_runtime.h>
#include <hip/hip_bf16.h>

#define NS   256
#define DIN  512
#define DHID 1024

typedef __attribute__((ext_vector_type(8))) short bf16x8;
typedef __attribute__((ext_vector_type(4))) float f32x4;

static __device__ __forceinline__ short f2bf(float f) {
    __hip_bfloat16 h = __float2bfloat16(f);   // RNE
    return __builtin_bit_cast(short, h);
}

static __device__ __forceinline__ bf16x8 cvt8(f32x4 a, f32x4 b) {
    bf16x8 r;
    r[0] = f2bf(a[0]); r[1] = f2bf(a[1]); r[2] = f2bf(a[2]); r[3] = f2bf(a[3]);
    r[4] = f2bf(b[0]); r[5] = f2bf(b[1]); r[6] = f2bf(b[2]); r[7] = f2bf(b[3]);
    return r;
}

// ---------------- Kernel 0: W1 [512,1024] f32 -> W1bT [1024,512] bf16 ----------------
// 64K threads; lane-consecutive n => coalesced row reads of W1; 16B stores per thread.
__global__ __launch_bounds__(256) void convertW_kernel(
    const float* __restrict__ W1, short* __restrict__ W1bT)
{
    const int g  = blockIdx.x * 256 + threadIdx.x;   // 0..65535
    const int n  = g & (DHID - 1);                   // 0..1023 (lane-consecutive)
    const int kg = g >> 10;                          // 0..63
    bf16x8 o;
    #pragma unroll
    for (int i = 0; i < 8; ++i)
        o[i] = f2bf(W1[(kg * 8 + i) * DHID + n]);
    *reinterpret_cast<bf16x8*>(W1bT + n * DIN + kg * 8) = o;
}

// ---------------- Kernel 1: feature pass (MFMA) ----------------
// Z = [x1;x2] @ W1 + b1 ; Hb = relu(Z) bf16 ; Gb = (Z>0)*w2 bf16
// grid (16,16): bid.x = 64-col tile, bid.y = 32-row tile. 4 waves: 2x2, each 16x32.
__global__ __launch_bounds__(256) void feat_kernel(
    const float* __restrict__ x1, const float* __restrict__ x2,
    const short* __restrict__ W1bT,
    const float* __restrict__ b1, const float* __restrict__ w2,
    short* __restrict__ Hb, short* __restrict__ Gb)
{
    const int tid = threadIdx.x;
    const int l   = tid & 63;
    const int w   = tid >> 6;
    const int lr  = l & 15;          // fragment lane row/col
    const int kg  = l >> 4;          // k-group 0..3 (also D-row group)
    const int m0  = blockIdx.y * 32 + (w >> 1) * 16;
    const int n0  = blockIdx.x * 64 + (w & 1) * 32;

    const float* X = (m0 < NS) ? (x1 + (size_t)m0 * DIN)
                               : (x2 + (size_t)(m0 - NS) * DIN);
    const float* arow  = X + lr * DIN + kg * 8;
    const short* brow0 = W1bT + (n0 + lr) * DIN + kg * 8;
    const short* brow1 = brow0 + 16 * DIN;

    f32x4 acc0 = {0.f, 0.f, 0.f, 0.f};
    f32x4 acc1 = {0.f, 0.f, 0.f, 0.f};
    #pragma unroll 4
    for (int t = 0; t < 16; ++t) {
        const int k = t * 32;
        f32x4 fa0 = *reinterpret_cast<const f32x4*>(arow + k);
        f32x4 fa1 = *reinterpret_cast<const f32x4*>(arow + k + 4);
        bf16x8 a  = cvt8(fa0, fa1);
        bf16x8 b0 = *reinterpret_cast<const bf16x8*>(brow0 + k);
        bf16x8 b1f= *reinterpret_cast<const bf16x8*>(brow1 + k);
        acc0 = __builtin_amdgcn_mfma_f32_16x16x32_bf16(a, b0,  acc0, 0, 0, 0);
        acc1 = __builtin_amdgcn_mfma_f32_16x16x32_bf16(a, b1f, acc1, 0, 0, 0);
    }

    // epilogue: D col = l&15, row = (l>>4)*4 + r  [m89]
    const int c0 = n0 + lr, c1 = n0 + 16 + lr;
    const float bb0 = b1[c0], ww0 = w2[c0];
    const float bb1 = b1[c1], ww1 = w2[c1];
    #pragma unroll
    for (int r = 0; r < 4; ++r) {
        const int row = m0 + kg * 4 + r;
        float z0 = acc0[r] + bb0;
        float z1 = acc1[r] + bb1;
        Hb[row * DHID + c0] = f2bf(z0 > 0.f ? z0  : 0.f);
        Gb[row * DHID + c0] = f2bf(z0 > 0.f ? ww0 : 0.f);
        Hb[row * DHID + c1] = f2bf(z1 > 0.f ? z1  : 0.f);
        Gb[row * DHID + c1] = f2bf(z1 > 0.f ? ww1 : 0.f);
    }
}

// ---------------- Kernel 2: fused gram + combine (MFMA, K-split over waves) ----------------
// out[i][j] = (x1_i.x2_j + 1)*(g1_i.g2_j) + h1_i.h2_j + 1
// grid (16,16): one 16x16 output tile per block; 4 waves split the 80 k-steps.
__global__ __launch_bounds__(256) void gram_kernel(
    const float* __restrict__ x1, const float* __restrict__ x2,
    const short* __restrict__ Hb, const short* __restrict__ Gb,
    float* __restrict__ out)
{
    const int tid = threadIdx.x;
    const int l   = tid & 63;
    const int w   = tid >> 6;
    const int lr  = l & 15;
    const int kg  = l >> 4;
    const int bi  = blockIdx.y * 16;
    const int bj  = blockIdx.x * 16;

    f32x4 ac = {0.f,0.f,0.f,0.f}, ag = {0.f,0.f,0.f,0.f}, ah = {0.f,0.f,0.f,0.f};

    // ---- c = x1 . x2 (K=512, 16 ksteps, 4 per wave) ----
    const float* ar = x1 + (bi + lr) * DIN + kg * 8;
    const float* br = x2 + (bj + lr) * DIN + kg * 8;
    #pragma unroll
    for (int t = 0; t < 4; ++t) {
        const int k = (w + t * 4) * 32;
        bf16x8 a = cvt8(*reinterpret_cast<const f32x4*>(ar + k),
                        *reinterpret_cast<const f32x4*>(ar + k + 4));
        bf16x8 b = cvt8(*reinterpret_cast<const f32x4*>(br + k),
                        *reinterpret_cast<const f32x4*>(br + k + 4));
        ac = __builtin_amdgcn_mfma_f32_16x16x32_bf16(a, b, ac, 0, 0, 0);
    }

    // ---- g = g1 . g2 (K=1024, 32 ksteps, 8 per wave) ----
    const short* ga = Gb + (bi + lr) * DHID + kg * 8;
    const short* gb = Gb + (NS + bj + lr) * DHID + kg * 8;
    #pragma unroll
    for (int t = 0; t < 8; ++t) {
        const int k = (w + t * 4) * 32;
        bf16x8 a = *reinterpret_cast<const bf16x8*>(ga + k);
        bf16x8 b = *reinterpret_cast<const bf16x8*>(gb + k);
        ag = __builtin_amdgcn_mfma_f32_16x16x32_bf16(a, b, ag, 0, 0, 0);
    }

    // ---- h = h1 . h2 (K=1024, 32 ksteps, 8 per wave) ----
    const short* ha = Hb + (bi + lr) * DHID + kg * 8;
    const short* hb = Hb + (NS + bj + lr) * DHID + kg * 8;
    #pragma unroll
    for (int t = 0; t < 8; ++t) {
        const int k = (w + t * 4) * 32;
        bf16x8 a = *reinterpret_cast<const bf16x8*>(ha + k);
        bf16x8 b = *reinterpret_cast<const bf16x8*>(hb + k);
        ah = __builtin_amdgcn_mfma_f32_16x16x32_bf16(a, b, ah, 0, 0, 0);
    }

    // ---- cross-wave reduce + combine ----
    __shared__ f32x4 red[3][4][64];   // 12 KiB
    red[0][w][l] = ac; red[1][w][l] = ag; red[2][w][l] = ah;
    __syncthreads();
    if (w == 0) {
        f32x4 c = red[0][0][l], g = red[1][0][l], h = red[2][0][l];
        #pragma unroll
        for (int q = 1; q < 4; ++q) {
            c += red[0][q][l]; g += red[1][q][l]; h += red[2][q][l];
        }
        #pragma unroll
        for (int r = 0; r < 4; ++r) {
            const int row = bi + kg * 4 + r;
            const int col = bj + lr;
            out[row * NS + col] = (c[r] + 1.f) * g[r] + h[r] + 1.f;
        }
    }
}

extern "C" void kernel_launch(void* const* d_in, const int* in_sizes, int n_in,
                              void* d_out, int out_size, void* d_ws, size_t ws_size,
                              hipStream_t stream) {
    const float* x1 = (const float*)d_in[0];   // [256,512]
    const float* x2 = (const float*)d_in[1];   // [256,512]
    const float* W1 = (const float*)d_in[2];   // [512,1024]
    const float* b1 = (const float*)d_in[3];   // [1024]
    const float* w2 = (const float*)d_in[4];   // [1024,1]
    // d_in[5] = b2: d f / d b2 == 1 always -> the "+1" term.

    short* W1bT = (short*)d_ws;                // [1024,512] bf16, 1 MiB
    short* Hb   = W1bT + DHID * DIN;           // [512,1024] bf16, 1 MiB
    short* Gb   = Hb   + 2 * NS * DHID;        // [512,1024] bf16, 1 MiB
    float* out  = (float*)d_out;               // [256,256]

    convertW_kernel<<<256, 256, 0, stream>>>(W1, W1bT);
    feat_kernel<<<dim3(16, 16), 256, 0, stream>>>(x1, x2, W1bT, b1, w2, Hb, Gb);
    gram_kernel<<<dim3(16, 16), 256, 0, stream>>>(x1, x2, Hb, Gb, out);
}